// Round 1
// baseline (258.971 us; speedup 1.0000x reference)
//
#include <hip/hip_runtime.h>

// Inv2d: out[b,g,c,i,j] = sum_{ki,kj,m} ker[b,g,ki*3+kj,i,m] * xpad[b,g*16+c, m+ki-1, j+kj-1]
//   ker = (W_span@W_reduce) @ x + (W_span@b_reduce + b_span)
// Reduction: Abar[b,g,d,i,r] = sum_ki ker[b, g*9+ki*3+d, i, r-(ki-1)]  (zero OOB)
//            out[b,g*16+c,i,j] = sum_d sum_r Abar[d][i,r] * X_c[r, j+d-1]  (zero OOB cols)

#define CH    256
#define G_    16
#define O_RED 128
#define KKG   144
#define BATCH 8
#define HW    4096
#define W64   64
#define MC_P  68   // padded stride for Mc/ker LDS rows (kills stride-64 bank aliasing)
#define AT_P  68   // padded stride for transposed Abar LDS

// ---------------- Kernel A: M = W_span @ W_reduce (144x256); bias = W_span@b_reduce + b_span
__global__ __launch_bounds__(256) void fuse_weights_k(
    const float* __restrict__ Wr, const float* __restrict__ br,
    const float* __restrict__ Ws, const float* __restrict__ bs,
    float* __restrict__ M, float* __restrict__ bias)
{
    __shared__ float ws[O_RED];
    const int k = blockIdx.x;
    const int c = threadIdx.x;
    if (c < O_RED) ws[c] = Ws[k * O_RED + c];
    __syncthreads();
    float acc = 0.f;
#pragma unroll 8
    for (int o = 0; o < O_RED; ++o)
        acc += ws[o] * Wr[o * CH + c];
    M[k * CH + c] = acc;
    if (c == 0) {
        float bb = bs[k];
        for (int o = 0; o < O_RED; ++o) bb += ws[o] * br[o];
        bias[k] = bb;
    }
}

// ---------------- Kernel B: per (b, row i): ker_row[144][64] = M @ x_row + bias, then
// Abar[b,g,d,i,r] = sum_ki ker_row[g*9+ki*3+d][r-(ki-1)]
__global__ __launch_bounds__(256) void ker_abar_k(
    const float* __restrict__ x, const float* __restrict__ M,
    const float* __restrict__ bias, float* __restrict__ Abar)
{
    __shared__ float xs[CH][W64];     // 64 KB: x[b, :, i, :]
    __shared__ float Mc[KKG][MC_P];   // 39.2 KB: M column-chunk; reused as ker_row
    __shared__ float bias_s[KKG];
    const int b = blockIdx.x >> 6;
    const int i = blockIdx.x & 63;
    const int t = threadIdx.x;
    if (t < KKG) bias_s[t] = bias[t];
    {   // stage x row i, all 256 channels (float4, coalesced)
        const float* xb = x + (size_t)b * CH * HW + i * W64;
        for (int q = t; q < CH * 16; q += 256) {
            int c = q >> 4, m4 = q & 15;
            float4 v = *(const float4*)(xb + (size_t)c * HW + m4 * 4);
            *(float4*)(&xs[c][m4 * 4]) = v;
        }
    }
    const int mq = t & 15;   // m = mq*4 + mm
    const int kg = t >> 4;   // k = kg*9 + kk
    float acc[9][4];
#pragma unroll
    for (int a = 0; a < 9; ++a)
#pragma unroll
        for (int mm = 0; mm < 4; ++mm) acc[a][mm] = 0.f;

    for (int c0 = 0; c0 < CH; c0 += 64) {
        __syncthreads();
        for (int q = t; q < KKG * 16; q += 256) {   // stage M[:, c0:c0+64]
            int k = q >> 4, c4 = q & 15;
            *(float4*)(&Mc[k][c4 * 4]) = *(const float4*)(M + k * CH + c0 + c4 * 4);
        }
        __syncthreads();
#pragma unroll 4
        for (int cc = 0; cc < 64; cc += 4) {
            float4 xr0 = *(const float4*)(&xs[c0 + cc + 0][mq * 4]);
            float4 xr1 = *(const float4*)(&xs[c0 + cc + 1][mq * 4]);
            float4 xr2 = *(const float4*)(&xs[c0 + cc + 2][mq * 4]);
            float4 xr3 = *(const float4*)(&xs[c0 + cc + 3][mq * 4]);
#pragma unroll
            for (int kk = 0; kk < 9; ++kk) {
                float4 mv = *(const float4*)(&Mc[kg * 9 + kk][cc]);
                acc[kk][0] += mv.x * xr0.x + mv.y * xr1.x + mv.z * xr2.x + mv.w * xr3.x;
                acc[kk][1] += mv.x * xr0.y + mv.y * xr1.y + mv.z * xr2.y + mv.w * xr3.y;
                acc[kk][2] += mv.x * xr0.z + mv.y * xr1.z + mv.z * xr2.z + mv.w * xr3.z;
                acc[kk][3] += mv.x * xr0.w + mv.y * xr1.w + mv.z * xr2.w + mv.w * xr3.w;
            }
        }
    }
    __syncthreads();
    // ker_row (+bias) into Mc
#pragma unroll
    for (int kk = 0; kk < 9; ++kk) {
        int k = kg * 9 + kk;
        float bb = bias_s[k];
#pragma unroll
        for (int mm = 0; mm < 4; ++mm)
            Mc[k][mq * 4 + mm] = acc[kk][mm] + bb;
    }
    __syncthreads();
    // Abar build + write: 48 (g,d) combos x 64 r
    float* Ao = Abar + (size_t)b * G_ * 3 * HW + (size_t)i * W64;
    for (int v = t; v < 48 * 64; v += 256) {
        int r = v & 63;
        int gd = v >> 6;             // 0..47
        int g = gd / 3, d = gd - 3 * g;
        float s = 0.f;
        if (r < 63) s += Mc[g * 9 + 0 + d][r + 1];   // ki=0 -> col r+1
        s += Mc[g * 9 + 3 + d][r];                   // ki=1 -> col r
        if (r > 0)  s += Mc[g * 9 + 6 + d][r - 1];   // ki=2 -> col r-1
        Ao[(size_t)(g * 3 + d) * HW + r] = s;
    }
}

// ---------------- Kernel C: per (b,g, 4-channel group):
// out[c,i,j] = sum_d sum_m Abar[d][i,m] * X_c[m, j+d-1]
__global__ __launch_bounds__(256) void inv_main_k(
    const float* __restrict__ x, const float* __restrict__ Abar,
    float* __restrict__ out)
{
    __shared__ float AT[3][W64][AT_P];  // 52.2 KB: AT[d][m][i] = Abar[d][i][m]
    __shared__ float Xs[4][W64][W64];   // 64 KB: 4 channel images
    const int t = threadIdx.x;
    const int cg = blockIdx.x & 3;
    const int bg = blockIdx.x >> 2;     // b*16 + g
    const int g = bg & 15;
    const int b = bg >> 4;
    {   // stage Abar transposed
        const float* Ab = Abar + (size_t)bg * 3 * HW;
        for (int q = t; q < 3 * HW; q += 256) {
            int d = q >> 12;
            int rem = q & 4095;
            int ii = rem >> 6, m = rem & 63;
            AT[d][m][ii] = Ab[q];
        }
    }
    const int ch_l = t >> 6;            // one wave per channel
    const int lane = t & 63;
    const int ch = g * 16 + cg * 4 + ch_l;
    {   // stage X: each wave loads its channel image (float4, coalesced)
        const float4* xp = (const float4*)(x + ((size_t)b * CH + ch) * HW);
        float4* xl = (float4*)(&Xs[ch_l][0][0]);
#pragma unroll
        for (int q = 0; q < 16; ++q) xl[lane + q * 64] = xp[lane + q * 64];
    }
    __syncthreads();

    const int i4 = (t & 63) >> 2;  // rows i4*4 .. +4
    const int jq = t & 3;          // cols jq*16 .. +16
    float acc[4][16];
#pragma unroll
    for (int a = 0; a < 4; ++a)
#pragma unroll
        for (int j = 0; j < 16; ++j) acc[a][j] = 0.f;

    for (int m = 0; m < 64; ++m) {
        float4 a0 = *(const float4*)(&AT[0][m][i4 * 4]);
        float4 a1 = *(const float4*)(&AT[1][m][i4 * 4]);
        float4 a2 = *(const float4*)(&AT[2][m][i4 * 4]);
        float4 x0 = *(const float4*)(&Xs[ch_l][m][jq * 16]);
        float4 x1 = *(const float4*)(&Xs[ch_l][m][jq * 16 + 4]);
        float4 x2 = *(const float4*)(&Xs[ch_l][m][jq * 16 + 8]);
        float4 x3 = *(const float4*)(&Xs[ch_l][m][jq * 16 + 12]);
        float xv[18];
        xv[0]  = (jq > 0) ? Xs[ch_l][m][jq * 16 - 1]  : 0.f;
        xv[17] = (jq < 3) ? Xs[ch_l][m][jq * 16 + 16] : 0.f;
        xv[1] = x0.x;  xv[2] = x0.y;  xv[3] = x0.z;  xv[4] = x0.w;
        xv[5] = x1.x;  xv[6] = x1.y;  xv[7] = x1.z;  xv[8] = x1.w;
        xv[9] = x2.x;  xv[10] = x2.y; xv[11] = x2.z; xv[12] = x2.w;
        xv[13] = x3.x; xv[14] = x3.y; xv[15] = x3.z; xv[16] = x3.w;
        float A0[4] = {a0.x, a0.y, a0.z, a0.w};
        float A1[4] = {a1.x, a1.y, a1.z, a1.w};
        float A2[4] = {a2.x, a2.y, a2.z, a2.w};
#pragma unroll
        for (int ii = 0; ii < 4; ++ii) {
#pragma unroll
            for (int jj = 0; jj < 16; ++jj)
                acc[ii][jj] += A0[ii] * xv[jj] + A1[ii] * xv[jj + 1] + A2[ii] * xv[jj + 2];
        }
    }
    // store
    float* op = out + ((size_t)b * CH + ch) * HW;
#pragma unroll
    for (int ii = 0; ii < 4; ++ii) {
        int row = i4 * 4 + ii;
#pragma unroll
        for (int jf = 0; jf < 4; ++jf) {
            float4 v = make_float4(acc[ii][jf * 4 + 0], acc[ii][jf * 4 + 1],
                                   acc[ii][jf * 4 + 2], acc[ii][jf * 4 + 3]);
            *(float4*)(&op[row * W64 + jq * 16 + jf * 4]) = v;
        }
    }
}

extern "C" void kernel_launch(void* const* d_in, const int* in_sizes, int n_in,
                              void* d_out, int out_size, void* d_ws, size_t ws_size,
                              hipStream_t stream)
{
    const float* x  = (const float*)d_in[0];
    const float* Wr = (const float*)d_in[1];   // (128,256)
    const float* br = (const float*)d_in[2];   // (128,)
    const float* Ws = (const float*)d_in[3];   // (144,128)
    const float* bs = (const float*)d_in[4];   // (144,)
    float* out = (float*)d_out;

    char* ws = (char*)d_ws;
    float* M    = (float*)(ws);             // 144*256*4 = 147456 B
    float* bias = (float*)(ws + 147456);    // 576 B
    float* Abar = (float*)(ws + 148480);    // 8*16*3*4096*4 = 6291456 B

    fuse_weights_k<<<dim3(KKG), dim3(256), 0, stream>>>(Wr, br, Ws, bs, M, bias);
    ker_abar_k<<<dim3(BATCH * 64), dim3(256), 0, stream>>>(x, M, bias, Abar);
    inv_main_k<<<dim3(BATCH * G_ * 4), dim3(256), 0, stream>>>(x, Abar, out);
}

// Round 3
// 182.469 us; speedup vs baseline: 1.4193x; 1.4193x over previous
//
#include <hip/hip_runtime.h>

typedef unsigned short ushort_t;
typedef unsigned int uint_t;
typedef __attribute__((ext_vector_type(8))) short bf16x8;   // 8 bf16 = 4 VGPR
typedef __attribute__((ext_vector_type(4))) float f32x4;

#define CH    256
#define ORED  128
#define KKG   144
#define BATCH 8
#define HW    4096
#define W64   64
#define PADA  88    // ushort stride for Abuf/Bbuf rows (176 B, 16B-aligned rows)
#define CSP   132   // ushort stride for epilogue ker dump

__device__ __forceinline__ ushort_t f2bf(float f) {          // RNE float->bf16
    uint_t u = __float_as_uint(f);
    u += 0x7FFFu + ((u >> 16) & 1u);
    return (ushort_t)(u >> 16);
}
__device__ __forceinline__ float bf2f(ushort_t u) {
    return __uint_as_float(((uint_t)u) << 16);
}

// ---------------- Kernel A: Mbf = bf16(W_span @ W_reduce); biasF = W_span@b_reduce + b_span
__global__ __launch_bounds__(256) void fuse_weights_k(
    const float* __restrict__ Wr, const float* __restrict__ br,
    const float* __restrict__ Ws, const float* __restrict__ bs,
    ushort_t* __restrict__ Mbf, float* __restrict__ biasF)
{
    __shared__ float ws[ORED];
    const int k = blockIdx.x;
    const int c = threadIdx.x;
    if (c < ORED) ws[c] = Ws[k * ORED + c];
    __syncthreads();
    float acc = 0.f;
#pragma unroll 8
    for (int o = 0; o < ORED; ++o)
        acc += ws[o] * Wr[o * CH + c];
    Mbf[k * CH + c] = f2bf(acc);
    if (c == 0) {
        float bb = bs[k];
        for (int o = 0; o < ORED; ++o) bb += ws[o] * br[o];
        biasF[k] = bb;
    }
}

// ---------------- Kernel B (MFMA): per (b, jt): C[144][128] = M @ X[:, jt*128..+128), +bias,
// then Abar[b, g*3+d][spatial] = sum_ki ker[g*9+ki*3+d][col shifted] (bf16 out)
__global__ __launch_bounds__(256) void gemm_abar_k(
    const float* __restrict__ x, const ushort_t* __restrict__ Mbf,
    const float* __restrict__ biasF, ushort_t* __restrict__ Abar)
{
    // arena: staging Abuf[144][PADA] + Bbuf[128][PADA]; epilogue aliases Cs[144][CSP]
    __shared__ __align__(16) ushort_t AB[KKG * PADA + 128 * PADA]; // 47872 B
    __shared__ float bias_s[KKG];
    ushort_t* Abuf = AB;
    ushort_t* Bbuf = AB + KKG * PADA;
    ushort_t* Cs   = AB;                 // [144][132] = 38016 B, fits

    const int b    = blockIdx.x >> 5;
    const int jt   = blockIdx.x & 31;
    const int col0 = jt * 128;
    const int t    = threadIdx.x;
    const int lane = t & 63;
    const int wv   = t >> 6;
    if (t < KKG) bias_s[t] = biasF[t];

    f32x4 acc[9][2];
#pragma unroll
    for (int rt = 0; rt < 9; ++rt)
#pragma unroll
        for (int ct = 0; ct < 2; ++ct) acc[rt][ct] = (f32x4)0.f;

    const int n_st  = t & 127;   // col within tile for X staging
    const int khalf = t >> 7;    // k-half for X staging

    for (int kc = 0; kc < 4; ++kc) {
        const int c0 = kc * 64;
        __syncthreads();
        // stage M[:, c0..c0+64) -> Abuf (bf16, already bf16 in global)
        for (int q = t; q < KKG * 16; q += 256) {
            int row = q >> 4, c4 = q & 15;
            uint2 v = *(const uint2*)(Mbf + row * CH + c0 + c4 * 4);
            *(uint2*)(Abuf + row * PADA + c4 * 4) = v;
        }
        // stage X chunk transposed: Bbuf[n][k] = bf16(x[b, c0+k, col0+n])
        {
            const float* xb = x + ((size_t)b * CH + c0 + khalf * 32) * HW + col0 + n_st;
            ushort_t* bp = Bbuf + n_st * PADA + khalf * 32;
#pragma unroll
            for (int kk = 0; kk < 32; kk += 2) {
                float f0 = xb[(size_t)kk * HW];
                float f1 = xb[(size_t)(kk + 1) * HW];
                uint_t u = (uint_t)f2bf(f0) | ((uint_t)f2bf(f1) << 16);
                *(uint_t*)(bp + kk) = u;
            }
        }
        __syncthreads();
        // compute: 2 K=32 steps
#pragma unroll
        for (int ks = 0; ks < 2; ++ks) {
            const int koff = ((lane >> 4) << 3) + ks * 32;
            bf16x8 b0 = *(const bf16x8*)(Bbuf + (wv * 32 + (lane & 15)) * PADA + koff);
            bf16x8 b1 = *(const bf16x8*)(Bbuf + (wv * 32 + 16 + (lane & 15)) * PADA + koff);
#pragma unroll
            for (int rt = 0; rt < 9; ++rt) {
                bf16x8 a = *(const bf16x8*)(Abuf + (rt * 16 + (lane & 15)) * PADA + koff);
                acc[rt][0] = __builtin_amdgcn_mfma_f32_16x16x32_bf16(a, b0, acc[rt][0], 0, 0, 0);
                acc[rt][1] = __builtin_amdgcn_mfma_f32_16x16x32_bf16(a, b1, acc[rt][1], 0, 0, 0);
            }
        }
    }
    __syncthreads();
    // dump ker = C + bias into Cs (bf16). D layout: col=lane&15, row=quad*4+reg
#pragma unroll
    for (int rt = 0; rt < 9; ++rt)
#pragma unroll
        for (int ct = 0; ct < 2; ++ct) {
            int col = wv * 32 + ct * 16 + (lane & 15);
            int rbase = rt * 16 + ((lane >> 4) << 2);
#pragma unroll
            for (int r = 0; r < 4; ++r)
                Cs[(rbase + r) * CSP + col] = f2bf(acc[rt][ct][r] + bias_s[rbase + r]);
        }
    __syncthreads();
    // Abar: 48 (g,d) x 128 cols
    ushort_t* Ao = Abar + (size_t)b * 48 * HW + col0;
    for (int v = t; v < 48 * 128; v += 256) {
        int gd = v >> 7, cl = v & 127;
        int m = cl & 63;
        int g = gd / 3, d = gd - g * 3;
        int r0 = g * 9 + d;
        float s = bf2f(Cs[(r0 + 3) * CSP + cl]);                 // ki=1
        if (m < 63) s += bf2f(Cs[r0 * CSP + cl + 1]);            // ki=0 -> col+1
        if (m > 0)  s += bf2f(Cs[(r0 + 6) * CSP + cl - 1]);      // ki=2 -> col-1
        Ao[(size_t)gd * HW + cl] = f2bf(s);
    }
}

// ---------------- Kernel C: per (b,g, channel-pair):
// out[c,i,j] = sum_d sum_m AT[d][m][i] * X_c[m, j+d-1]   (fp32 math, bf16 LDS)
__global__ __launch_bounds__(256) void inv_main_k(
    const float* __restrict__ x, const ushort_t* __restrict__ Abar,
    float* __restrict__ out)
{
    __shared__ ushort_t ATb[3 * 64 * 68];   // 26112 B, AT[d][m][i]
    __shared__ ushort_t Xs[2 * HW];         // 16384 B
    const int t = threadIdx.x;
    const int bg = blockIdx.x >> 3, cp = blockIdx.x & 7;
    const int b = bg >> 4, g = bg & 15;
    const int ch0 = g * 16 + cp * 2;

    {   // stage AT transposed (uint loads = 2 bf16 along m)
        const ushort_t* Ab = Abar + ((size_t)b * 48 + g * 3) * HW;
        for (int q2 = t; q2 < 6144; q2 += 256) {
            uint_t u = *(const uint_t*)(Ab + q2 * 2);
            int e = q2 * 2;
            int d = e >> 12, ii = (e >> 6) & 63, m = e & 63;
            ATb[d * 4352 + m * 68 + ii]       = (ushort_t)(u & 0xFFFFu);
            ATb[d * 4352 + (m + 1) * 68 + ii] = (ushort_t)(u >> 16);
        }
    }
    {   // stage 2 channel images as bf16
        const float* xb = x + ((size_t)b * CH + ch0) * HW;
        for (int q = t; q < 2048; q += 256) {
            float4 v = ((const float4*)xb)[q];
            ushort_t* dst = Xs + q * 4;
            dst[0] = f2bf(v.x); dst[1] = f2bf(v.y);
            dst[2] = f2bf(v.z); dst[3] = f2bf(v.w);
        }
    }
    __syncthreads();

    const int ch_l = t >> 7, tl = t & 127;
    const int i2 = tl >> 2;   // rows i2*2, i2*2+1
    const int jq = tl & 3;    // cols jq*16 .. +16
    float acc[2][16];
#pragma unroll
    for (int r = 0; r < 2; ++r)
#pragma unroll
        for (int j = 0; j < 16; ++j) acc[r][j] = 0.f;

    const ushort_t* Xrow = Xs + ch_l * HW;
    for (int m = 0; m < 64; ++m) {
        uint_t ua0 = *(const uint_t*)(ATb + m * 68 + i2 * 2);
        uint_t ua1 = *(const uint_t*)(ATb + 4352 + m * 68 + i2 * 2);
        uint_t ua2 = *(const uint_t*)(ATb + 8704 + m * 68 + i2 * 2);
        float A0[2] = { __uint_as_float(ua0 << 16), __uint_as_float(ua0 & 0xFFFF0000u) };
        float A1[2] = { __uint_as_float(ua1 << 16), __uint_as_float(ua1 & 0xFFFF0000u) };
        float A2[2] = { __uint_as_float(ua2 << 16), __uint_as_float(ua2 & 0xFFFF0000u) };
        const ushort_t* xr = Xrow + m * 64 + jq * 16;
        float xv[18];
        xv[0]  = (jq > 0) ? bf2f(xr[-1]) : 0.f;
        xv[17] = (jq < 3) ? bf2f(xr[16]) : 0.f;
#pragma unroll
        for (int e = 0; e < 4; ++e) {
            uint2 u = *(const uint2*)(xr + e * 4);
            xv[1 + e * 4 + 0] = __uint_as_float(u.x << 16);
            xv[1 + e * 4 + 1] = __uint_as_float(u.x & 0xFFFF0000u);
            xv[1 + e * 4 + 2] = __uint_as_float(u.y << 16);
            xv[1 + e * 4 + 3] = __uint_as_float(u.y & 0xFFFF0000u);
        }
#pragma unroll
        for (int r = 0; r < 2; ++r) {
#pragma unroll
            for (int jj = 0; jj < 16; ++jj)
                acc[r][jj] += A0[r] * xv[jj] + A1[r] * xv[jj + 1] + A2[r] * xv[jj + 2];
        }
    }
    // store
    float* op = out + ((size_t)b * CH + ch0 + ch_l) * HW;
#pragma unroll
    for (int r = 0; r < 2; ++r) {
        int row = i2 * 2 + r;
#pragma unroll
        for (int jf = 0; jf < 4; ++jf) {
            float4 v = make_float4(acc[r][jf * 4 + 0], acc[r][jf * 4 + 1],
                                   acc[r][jf * 4 + 2], acc[r][jf * 4 + 3]);
            *(float4*)(&op[row * W64 + jq * 16 + jf * 4]) = v;
        }
    }
}

extern "C" void kernel_launch(void* const* d_in, const int* in_sizes, int n_in,
                              void* d_out, int out_size, void* d_ws, size_t ws_size,
                              hipStream_t stream)
{
    const float* x  = (const float*)d_in[0];
    const float* Wr = (const float*)d_in[1];   // (128,256)
    const float* br = (const float*)d_in[2];   // (128,)
    const float* Ws = (const float*)d_in[3];   // (144,128)
    const float* bs = (const float*)d_in[4];   // (144,)
    float* out = (float*)d_out;

    char* ws = (char*)d_ws;
    ushort_t* Mbf  = (ushort_t*)(ws);              // 144*256*2 = 73728 B
    float*    bias = (float*)(ws + 73728);         // 576 B
    ushort_t* Abar = (ushort_t*)(ws + 77824);      // 8*48*4096*2 = 3145728 B

    fuse_weights_k<<<dim3(KKG), dim3(256), 0, stream>>>(Wr, br, Ws, bs, Mbf, bias);
    gemm_abar_k<<<dim3(BATCH * 32), dim3(256), 0, stream>>>(x, Mbf, bias, Abar);
    // 8 b * 16 g * 8 channel-pairs = 1024 blocks
    inv_main_k<<<dim3(1024), dim3(256), 0, stream>>>(x, Abar, out);
}

// Round 4
// 111.636 us; speedup vs baseline: 2.3198x; 1.6345x over previous
//
#include <hip/hip_runtime.h>

typedef unsigned short u16;
typedef unsigned int u32;
typedef __attribute__((ext_vector_type(8))) short bf16x8;   // 8 bf16 = 4 VGPR
typedef __attribute__((ext_vector_type(4))) float f32x4;

#define CH   256
#define KKG  144
#define HW   4096
#define CSP  132    // u16 stride for epilogue ker dump in LDS

__device__ __forceinline__ u16 f2bf(float f) {               // RNE float->bf16
    u32 u = __float_as_uint(f);
    u += 0x7FFFu + ((u >> 16) & 1u);
    return (u16)(u >> 16);
}
__device__ __forceinline__ float bf2f(u16 u) {
    return __uint_as_float(((u32)u) << 16);
}

// ---------------- Kernel A: M = W_span @ W_reduce (144x256) written in MFMA
// A-fragment-linear order Mfrag[ks(8)][mt(9)][lane(64)][8]; bias fused.
__global__ __launch_bounds__(256) void fuse_weights_k(
    const float* __restrict__ Wr, const float* __restrict__ br,
    const float* __restrict__ Ws, const float* __restrict__ bs,
    u16* __restrict__ Mfrag, float* __restrict__ biasF)
{
    __shared__ float ws[128];
    const int r = blockIdx.x;    // 0..143 (ker row)
    const int c = threadIdx.x;   // 0..255 (channel = K)
    if (c < 128) ws[c] = Ws[r * 128 + c];
    __syncthreads();
    float acc = 0.f;
#pragma unroll 8
    for (int o = 0; o < 128; ++o) acc += ws[o] * Wr[o * CH + c];
    // frag coords: k = c -> ks = c>>5, quad = (c>>3)&3, jj = c&7 ; m = r -> mt, lane
    const int ks = c >> 5, quad = (c >> 3) & 3, jj = c & 7;
    const int mt = r >> 4, lane = (r & 15) + (quad << 4);
    Mfrag[((ks * 9 + mt) * 64 + lane) * 8 + jj] = f2bf(acc);
    if (c == 0) {
        float bb = bs[r];
        for (int o = 0; o < 128; ++o) bb += ws[o] * br[o];
        biasF[r] = bb;
    }
}

// ---------------- Kernel B: per (b, 2 image rows): ker[144][128] = M @ X + bias via MFMA
// (B-frags gathered directly from global x, no LDS/barriers in K-loop), then the
// ki-shift recombine writes Abar in A-fragment-linear order: Afrag[bg][ks(6)][mt(4)][lane][8]
__global__ __launch_bounds__(256) void ker_abar_k(
    const float* __restrict__ x, const u16* __restrict__ Mfrag,
    const float* __restrict__ biasF, u16* __restrict__ Afrag)
{
    __shared__ u16 Cs[KKG * CSP];      // 38016 B
    __shared__ float bias_s[KKG];
    const int b = blockIdx.x >> 5, jt = blockIdx.x & 31;
    const int col0 = jt * 128;
    const int t = threadIdx.x, lane = t & 63, w = t >> 6;
    const int nl = lane & 15, quad = lane >> 4;
    if (t < KKG) bias_s[t] = biasF[t];

    f32x4 acc[9][2];
#pragma unroll
    for (int mt = 0; mt < 9; ++mt)
#pragma unroll
        for (int nt = 0; nt < 2; ++nt) acc[mt][nt] = (f32x4)0.f;

    const int n0 = col0 + w * 32;
    for (int ks = 0; ks < 8; ++ks) {
        bf16x8 a[9];
        const bf16x8* Ag = ((const bf16x8*)Mfrag) + (ks * 9) * 64 + lane;
#pragma unroll
        for (int mt = 0; mt < 9; ++mt) a[mt] = Ag[mt * 64];
#pragma unroll
        for (int nt = 0; nt < 2; ++nt) {
            const float* xb = x + ((size_t)(b * CH + ks * 32 + quad * 8)) * HW + n0 + nt * 16 + nl;
            float f0 = xb[0],        f1 = xb[(size_t)HW],
                  f2 = xb[2*(size_t)HW], f3 = xb[3*(size_t)HW],
                  f4 = xb[4*(size_t)HW], f5 = xb[5*(size_t)HW],
                  f6 = xb[6*(size_t)HW], f7 = xb[7*(size_t)HW];
            union { bf16x8 v; uint4 u; } bb;
            bb.u.x = (u32)f2bf(f0) | ((u32)f2bf(f1) << 16);
            bb.u.y = (u32)f2bf(f2) | ((u32)f2bf(f3) << 16);
            bb.u.z = (u32)f2bf(f4) | ((u32)f2bf(f5) << 16);
            bb.u.w = (u32)f2bf(f6) | ((u32)f2bf(f7) << 16);
#pragma unroll
            for (int mt = 0; mt < 9; ++mt)
                acc[mt][nt] = __builtin_amdgcn_mfma_f32_16x16x32_bf16(a[mt], bb.v, acc[mt][nt], 0, 0, 0);
        }
    }
    __syncthreads();   // bias_s visible; Cs about to be written
    // dump ker = C + bias (D layout: col = lane&15, row = quad*4+reg)
#pragma unroll
    for (int mt = 0; mt < 9; ++mt)
#pragma unroll
        for (int nt = 0; nt < 2; ++nt) {
            const int colb = w * 32 + nt * 16 + nl;
            const int rb = mt * 16 + quad * 4;
#pragma unroll
            for (int reg = 0; reg < 4; ++reg)
                Cs[(rb + reg) * CSP + colb] = f2bf(acc[mt][nt][reg] + bias_s[rb + reg]);
        }
    __syncthreads();
    // Abar recombine + frag-linear store: 48 gd x 2 rows x 8 octs = 768 16B-chunks
    for (int v = t; v < 768; v += 256) {
        const int gd = v >> 4, rem = v & 15;
        const int il = rem >> 3, o = rem & 7;
        const int g = gd / 3, d = gd - g * 3;
        const int r0 = g * 9 + d;
        const int i = jt * 2 + il;          // image row 0..63
        const int base = il * 64 + o * 8;   // col base within Cs row
        u16 h[8];
#pragma unroll
        for (int e = 0; e < 8; ++e) {
            const int m = o * 8 + e;
            float s = bf2f(Cs[(r0 + 3) * CSP + base + e]);            // ki=1
            if (m < 63) s += bf2f(Cs[r0 * CSP + base + e + 1]);       // ki=0 -> col+1
            if (m > 0)  s += bf2f(Cs[(r0 + 6) * CSP + base + e - 1]); // ki=2 -> col-1
            h[e] = f2bf(s);
        }
        uint4 pk;
        pk.x = (u32)h[0] | ((u32)h[1] << 16);
        pk.y = (u32)h[2] | ((u32)h[3] << 16);
        pk.z = (u32)h[4] | ((u32)h[5] << 16);
        pk.w = (u32)h[6] | ((u32)h[7] << 16);
        const int ks2 = 2 * d + (o >> 2), quad2 = o & 3;
        const int mt2 = i >> 4, lane2 = (i & 15) + (quad2 << 4);
        const size_t idx = ((((size_t)(b * 16 + g) * 6 + ks2) * 4 + mt2) * 64 + lane2) * 8;
        *(uint4*)(Afrag + idx) = pk;
    }
}

// ---------------- Kernel C: per (b,g,quarter): out_c = Aall[64x192] @ XTc[192x64] via MFMA.
// XT[j][m] (bf16, XOR-swizzled 16B chunks) built per channel in LDS; A-frags from global.
__global__ __launch_bounds__(256) void inv_main_k(
    const float* __restrict__ x, const u16* __restrict__ Afrag,
    float* __restrict__ out)
{
    __shared__ u16 XT[4 * 4096];   // 32 KB: 4 channels, chunk(j,o) = j*8 + (o^(j&7))
    const int t = threadIdx.x;
    const int q = blockIdx.x & 3, bg = blockIdx.x >> 2;
    const int g = bg & 15, b = bg >> 4;
    const int ch_base = g * 16 + q * 4;

    // staging: 4 ch x 8 octs x 16 j-quads = 512 tasks (jq fastest for coalescing)
    for (int task = t; task < 512; task += 256) {
        const int ch = task >> 7, rem = task & 127;
        const int o = rem >> 4, jq = rem & 15;
        const float* xc = x + ((size_t)(b * CH + ch_base + ch)) * HW + o * 512 + jq * 4;
        float4 r0 = *(const float4*)(xc);
        float4 r1 = *(const float4*)(xc + 64);
        float4 r2 = *(const float4*)(xc + 128);
        float4 r3 = *(const float4*)(xc + 192);
        float4 r4 = *(const float4*)(xc + 256);
        float4 r5 = *(const float4*)(xc + 320);
        float4 r6 = *(const float4*)(xc + 384);
        float4 r7 = *(const float4*)(xc + 448);
        u16* base = XT + ch * 4096;
        uint4 pk;
        int j, chunk;
        // cc = 0 (component x)
        pk.x = (u32)f2bf(r0.x) | ((u32)f2bf(r1.x) << 16);
        pk.y = (u32)f2bf(r2.x) | ((u32)f2bf(r3.x) << 16);
        pk.z = (u32)f2bf(r4.x) | ((u32)f2bf(r5.x) << 16);
        pk.w = (u32)f2bf(r6.x) | ((u32)f2bf(r7.x) << 16);
        j = jq * 4 + 0; chunk = j * 8 + (o ^ (j & 7));
        *(uint4*)(base + chunk * 8) = pk;
        // cc = 1
        pk.x = (u32)f2bf(r0.y) | ((u32)f2bf(r1.y) << 16);
        pk.y = (u32)f2bf(r2.y) | ((u32)f2bf(r3.y) << 16);
        pk.z = (u32)f2bf(r4.y) | ((u32)f2bf(r5.y) << 16);
        pk.w = (u32)f2bf(r6.y) | ((u32)f2bf(r7.y) << 16);
        j = jq * 4 + 1; chunk = j * 8 + (o ^ (j & 7));
        *(uint4*)(base + chunk * 8) = pk;
        // cc = 2
        pk.x = (u32)f2bf(r0.z) | ((u32)f2bf(r1.z) << 16);
        pk.y = (u32)f2bf(r2.z) | ((u32)f2bf(r3.z) << 16);
        pk.z = (u32)f2bf(r4.z) | ((u32)f2bf(r5.z) << 16);
        pk.w = (u32)f2bf(r6.z) | ((u32)f2bf(r7.z) << 16);
        j = jq * 4 + 2; chunk = j * 8 + (o ^ (j & 7));
        *(uint4*)(base + chunk * 8) = pk;
        // cc = 3
        pk.x = (u32)f2bf(r0.w) | ((u32)f2bf(r1.w) << 16);
        pk.y = (u32)f2bf(r2.w) | ((u32)f2bf(r3.w) << 16);
        pk.z = (u32)f2bf(r4.w) | ((u32)f2bf(r5.w) << 16);
        pk.w = (u32)f2bf(r6.w) | ((u32)f2bf(r7.w) << 16);
        j = jq * 4 + 3; chunk = j * 8 + (o ^ (j & 7));
        *(uint4*)(base + chunk * 8) = pk;
    }
    __syncthreads();

    const int lane = t & 63, w = t >> 6;     // wave w -> local channel w
    const int nl = lane & 15, quad = lane >> 4;
    f32x4 acc[4][4];
#pragma unroll
    for (int mt = 0; mt < 4; ++mt)
#pragma unroll
        for (int nt = 0; nt < 4; ++nt) acc[mt][nt] = (f32x4)0.f;

    const u16* XTc = XT + w * 4096;
    for (int ks = 0; ks < 6; ++ks) {
        const int d = ks >> 1, mh = ks & 1;
        const bf16x8* Ag = ((const bf16x8*)Afrag) + ((size_t)(bg * 6 + ks) * 4) * 64 + lane;
        bf16x8 a0 = Ag[0], a1 = Ag[64], a2 = Ag[128], a3 = Ag[192];
        const int o = mh * 4 + quad;
#pragma unroll
        for (int nt = 0; nt < 4; ++nt) {
            const int jrow = nt * 16 + nl + d - 1;
            const int jc = jrow < 0 ? 0 : (jrow > 63 ? 63 : jrow);
            const int chunk = jc * 8 + (o ^ (jc & 7));
            bf16x8 bv = *(const bf16x8*)(XTc + chunk * 8);
            if (jrow < 0 || jrow > 63) bv = (bf16x8)(short)0;
            acc[0][nt] = __builtin_amdgcn_mfma_f32_16x16x32_bf16(a0, bv, acc[0][nt], 0, 0, 0);
            acc[1][nt] = __builtin_amdgcn_mfma_f32_16x16x32_bf16(a1, bv, acc[1][nt], 0, 0, 0);
            acc[2][nt] = __builtin_amdgcn_mfma_f32_16x16x32_bf16(a2, bv, acc[2][nt], 0, 0, 0);
            acc[3][nt] = __builtin_amdgcn_mfma_f32_16x16x32_bf16(a3, bv, acc[3][nt], 0, 0, 0);
        }
    }
    // store (D layout: col = nl, row = quad*4+reg)
    float* op = out + ((size_t)(b * CH + ch_base + w)) * HW;
#pragma unroll
    for (int mt = 0; mt < 4; ++mt)
#pragma unroll
        for (int nt = 0; nt < 4; ++nt)
#pragma unroll
            for (int reg = 0; reg < 4; ++reg)
                op[(mt * 16 + quad * 4 + reg) * 64 + nt * 16 + nl] = acc[mt][nt][reg];
}

extern "C" void kernel_launch(void* const* d_in, const int* in_sizes, int n_in,
                              void* d_out, int out_size, void* d_ws, size_t ws_size,
                              hipStream_t stream)
{
    const float* x  = (const float*)d_in[0];
    const float* Wr = (const float*)d_in[1];   // (128,256)
    const float* br = (const float*)d_in[2];   // (128,)
    const float* Ws = (const float*)d_in[3];   // (144,128)
    const float* bs = (const float*)d_in[4];   // (144,)
    float* out = (float*)d_out;

    char* ws = (char*)d_ws;
    u16*   Mfrag = (u16*)(ws);                 // 8*9*64*8*2 = 73728 B
    float* biasF = (float*)(ws + 73728);       // 576 B
    u16*   Afrag = (u16*)(ws + 81920);         // 128*6*4*64*8*2 = 3145728 B

    fuse_weights_k<<<dim3(KKG), dim3(256), 0, stream>>>(Wr, br, Ws, bs, Mfrag, biasF);
    ker_abar_k<<<dim3(256), dim3(256), 0, stream>>>(x, Mfrag, biasF, Afrag);   // 8 b * 32 row-pairs
    inv_main_k<<<dim3(512), dim3(256), 0, stream>>>(x, Afrag, out);            // 8 b * 16 g * 4 quarters
}